// Round 1
// baseline (140.625 us; speedup 1.0000x reference)
//
#include <hip/hip_runtime.h>
#include <hip/hip_bf16.h>
#include <math.h>

// Problem constants
#define N_TOK 16384
#define I_DIM 128
#define O_DIM 128
#define G_DIM 16
// GEMM tiling
#define BN 64                       // n-rows per block
#define CI 4                        // i-values per K-chunk
#define KC (CI * G_DIM * 2)         // 128 k per chunk
#define NCHUNK (I_DIM / CI)         // 32 chunks
#define A_STRIDE 136                // bf16 elems per LDS A row (272 B; 17*16B -> conflict-free)
#define ABUF (BN * A_STRIDE)        // elems per A buffer (17408 B)
#define C_STRIDE 132                // floats per LDS C row (epilogue)

typedef __bf16 bf16x8 __attribute__((ext_vector_type(8)));
typedef float  f32x4  __attribute__((ext_vector_type(4)));

// ---------------------------------------------------------------------------
// Pack cos/sin amplitudes (O,I,G) fp32 -> bf16 Bp[c][o][kk]
// kk = il*32 + g*2 + s   (il = i within chunk, s: 0=cos 1=sin)
// Vectorized: each thread emits 8 bf16 (one (il,gq) group) via 2x float4 loads.
// ---------------------------------------------------------------------------
__global__ __launch_bounds__(256) void fkan_pack_b(
    const float* __restrict__ cosA, const float* __restrict__ sinA,
    __bf16* __restrict__ Bp)
{
    int idx = blockIdx.x * 256 + threadIdx.x;   // 0 .. 65535
    int kk8 = idx & 15;                         // 8-elem group within the 128-k row
    int o   = (idx >> 4) & 127;
    int c   = idx >> 11;
    int il  = kk8 >> 2;
    int gq  = kk8 & 3;                          // g base = gq*4
    int i   = c * CI + il;
    size_t sbase = ((size_t)o * I_DIM + i) * G_DIM + gq * 4;
    float4 cv = *(const float4*)(cosA + sbase);
    float4 sv = *(const float4*)(sinA + sbase);
    bf16x8 v;
    v[0] = (__bf16)cv.x; v[1] = (__bf16)sv.x;
    v[2] = (__bf16)cv.y; v[3] = (__bf16)sv.y;
    v[4] = (__bf16)cv.z; v[5] = (__bf16)sv.z;
    v[6] = (__bf16)cv.w; v[7] = (__bf16)sv.w;
    *(bf16x8*)(Bp + (size_t)idx * 8) = v;
}

// ---------------------------------------------------------------------------
// Fused: features (cos/sin of x*freq) -> bf16 MFMA GEMM -> bias -> LayerNorm
// Grid: 256 blocks x 512 threads (8 waves). Block tile 64n x 128o. K = 4096.
// Wave tile: 32n x 32o (rg = wave>>2, cg = wave&3; mt=2 x ot=2 of 16x16x32).
// B fragments are wave-private -> loaded straight from global (L2-resident),
// double-buffered in registers. A feature tile double-buffered in LDS with
// ONE raw barrier per chunk (lgkmcnt-only drain keeps B prefetch in flight).
// ---------------------------------------------------------------------------
__global__ __launch_bounds__(512) void fkan_main(
    const float* __restrict__ x,
    const __bf16* __restrict__ Bp,
    const float* __restrict__ bias,
    const float* __restrict__ gamma,
    const float* __restrict__ beta,
    float* __restrict__ out)
{
    // LDS: 2 x A buffer (64 x 136 bf16 = 17408 B each) = 34816 B.
    // Epilogue C tile (64 x 132 f32 = 33792 B) reuses the same memory.
    __shared__ __align__(16) __bf16 smem[2 * ABUF];
    __bf16* A0 = smem;
    __bf16* A1 = smem + ABUF;

    const int t     = threadIdx.x;
    const int lane  = t & 63;
    const int wave  = t >> 6;          // 0..7
    const int rg    = wave >> 2;       // row-group (0..1): rows rg*32 .. rg*32+31
    const int cg    = wave & 3;        // col-group (0..3): cols cg*32 .. cg*32+31
    const int row16 = lane & 15;
    const int quad  = lane >> 4;
    const int n0    = blockIdx.x * BN;
    const int obase = cg * 32 + row16; // o-row this lane reads from Bp (+ot*16)

    // feature-staging role: (row, i-within-chunk, g-half). shalf is wave-uniform.
    const int srow  = (t & 255) >> 2;  // 0..63
    const int sil   = t & 3;           // 0..3
    const int shalf = t >> 8;          // 0: g=1..8, 1: g=9..16

    f32x4 acc[2][2];
#pragma unroll
    for (int mt = 0; mt < 2; ++mt)
#pragma unroll
        for (int ot = 0; ot < 2; ++ot)
            acc[mt][ot] = (f32x4){0.f, 0.f, 0.f, 0.f};

    bf16x8 bA[2][4], bB[2][4];         // [ot][ks] register double-buffer for B

    // ---- stage A features for chunk c into buffer Ab (all 512 threads) ----
    auto stage_a = [&](int c, __bf16* Ab) {
        float xv = x[(size_t)(n0 + srow) * I_DIM + (c * CI + sil)];
        float s1, c1;
        __sincosf(xv, &s1, &c1);
        float cb = c1, sb = s1;        // base = (cos x, sin x)  [g=1]
        if (shalf) {                   // base = (cos 9x, sin 9x) via 3 doublings + 1 step
            float cd = c1, sd = s1;
#pragma unroll
            for (int d = 0; d < 3; ++d) {
                float cn = cd * cd - sd * sd;
                float sn = 2.f * cd * sd;
                cd = cn; sd = sn;
            }
            cb = cd * c1 - sd * s1;
            sb = sd * c1 + cd * s1;
        }
        __align__(16) __bf16 feat[16];
        float cc_ = cb, ss_ = sb;
#pragma unroll
        for (int j = 0; j < 8; ++j) {  // g = base .. base+7, step by x
            feat[2 * j]     = (__bf16)cc_;
            feat[2 * j + 1] = (__bf16)ss_;
            float cn = cc_ * c1 - ss_ * s1;
            float sn = ss_ * c1 + cc_ * s1;
            cc_ = cn; ss_ = sn;
        }
        bf16x8* dst = (bf16x8*)(Ab + srow * A_STRIDE + sil * 32 + shalf * 16);
        dst[0] = ((const bf16x8*)feat)[0];
        dst[1] = ((const bf16x8*)feat)[1];
    };

    // ---- load this wave's B fragments for chunk c straight from global ----
    auto load_b = [&](int c, bf16x8 (&b)[2][4]) {
        const __bf16* p = Bp + (size_t)c * (O_DIM * KC) + (size_t)obase * KC + quad * 8;
#pragma unroll
        for (int ot = 0; ot < 2; ++ot)
#pragma unroll
            for (int ks = 0; ks < 4; ++ks)
                b[ot][ks] = *(const bf16x8*)(p + ot * (16 * KC) + ks * 32);
    };

    // ---- one K-chunk: read A frags, stage next A + prefetch next B, MFMA ----
    auto phase = [&](int c, const __bf16* Ar, __bf16* Aw,
                     bf16x8 (&bcur)[2][4], bf16x8 (&bnext)[2][4], bool do_next) {
        bf16x8 a[2][4];
#pragma unroll
        for (int mt = 0; mt < 2; ++mt)
#pragma unroll
            for (int ks = 0; ks < 4; ++ks)
                a[mt][ks] = *(const bf16x8*)(Ar + (rg * 32 + mt * 16 + row16) * A_STRIDE
                                             + ks * 32 + quad * 8);
        if (do_next) {
            stage_a(c + 1, Aw);        // VALU + ds_write (other buffer)
            load_b(c + 1, bnext);      // global loads stay in flight across barrier
        }
        asm volatile("s_waitcnt lgkmcnt(0)" ::: "memory"); // a-reads done + stage writes visible
        __builtin_amdgcn_sched_barrier(0);                 // rule #18: pin MFMA after the wait
        __builtin_amdgcn_s_setprio(1);
#pragma unroll
        for (int ks = 0; ks < 4; ++ks)
#pragma unroll
            for (int mt = 0; mt < 2; ++mt)
#pragma unroll
                for (int ot = 0; ot < 2; ++ot)
                    acc[mt][ot] = __builtin_amdgcn_mfma_f32_16x16x32_bf16(
                        a[mt][ks], bcur[ot][ks], acc[mt][ot], 0, 0, 0);
        __builtin_amdgcn_s_setprio(0);
        __builtin_amdgcn_s_barrier();  // raw barrier: publishes Aw, retires Ar reads; vmcnt NOT drained
    };

    // prologue
    stage_a(0, A0);
    load_b(0, bA);
    asm volatile("s_waitcnt lgkmcnt(0)" ::: "memory");
    __builtin_amdgcn_s_barrier();

    for (int cc = 0; cc < NCHUNK / 2; ++cc) {
        phase(2 * cc,     A0, A1, bA, bB, true);
        phase(2 * cc + 1, A1, A0, bB, bA, cc != NCHUNK / 2 - 1);
    }

    // ---- epilogue: acc -> LDS C, bias + LayerNorm over O=128, store fp32 ----
    // C/D layout: col(o within 16) = lane&15, row(m within 16) = quad*4 + reg
    float* Cs = (float*)smem;          // safe: last phase barrier retired all A reads
#pragma unroll
    for (int mt = 0; mt < 2; ++mt)
#pragma unroll
        for (int ot = 0; ot < 2; ++ot)
#pragma unroll
            for (int r = 0; r < 4; ++r)
                Cs[(rg * 32 + mt * 16 + quad * 4 + r) * C_STRIDE
                   + cg * 32 + ot * 16 + row16] = acc[mt][ot][r];
    __syncthreads();

    {
        const int r  = t >> 3;         // row within block (0..63)
        const int oc = t & 7;          // eighth of the O dim (16 cols each)
        const float* crow = Cs + r * C_STRIDE + oc * 16;
        float vals[16];
        float sum = 0.f, sumsq = 0.f;
#pragma unroll
        for (int j4 = 0; j4 < 4; ++j4) {
            f32x4 v4 = *(const f32x4*)(crow + 4 * j4);
#pragma unroll
            for (int e = 0; e < 4; ++e) {
                float v = v4[e] + bias[oc * 16 + 4 * j4 + e];
                vals[4 * j4 + e] = v;
                sum += v;
                sumsq += v * v;
            }
        }
        // combine the 8 threads of this row (adjacent lanes, bits 0-2)
        sum   += __shfl_xor(sum, 1);   sum   += __shfl_xor(sum, 2);   sum   += __shfl_xor(sum, 4);
        sumsq += __shfl_xor(sumsq, 1); sumsq += __shfl_xor(sumsq, 2); sumsq += __shfl_xor(sumsq, 4);
        float mu   = sum * (1.0f / O_DIM);
        float var  = sumsq * (1.0f / O_DIM) - mu * mu;
        float rstd = rsqrtf(var + 1e-5f);

        float* orow = out + (size_t)(n0 + r) * O_DIM + oc * 16;
#pragma unroll
        for (int j4 = 0; j4 < 4; ++j4) {
            float4 o4;
            o4.x = (vals[4*j4+0] - mu) * rstd * gamma[oc*16 + 4*j4+0] + beta[oc*16 + 4*j4+0];
            o4.y = (vals[4*j4+1] - mu) * rstd * gamma[oc*16 + 4*j4+1] + beta[oc*16 + 4*j4+1];
            o4.z = (vals[4*j4+2] - mu) * rstd * gamma[oc*16 + 4*j4+2] + beta[oc*16 + 4*j4+2];
            o4.w = (vals[4*j4+3] - mu) * rstd * gamma[oc*16 + 4*j4+3] + beta[oc*16 + 4*j4+3];
            *(float4*)(orow + 4 * j4) = o4;
        }
    }
}

extern "C" void kernel_launch(void* const* d_in, const int* in_sizes, int n_in,
                              void* d_out, int out_size, void* d_ws, size_t ws_size,
                              hipStream_t stream) {
    const float* x     = (const float*)d_in[0];
    const float* cosA  = (const float*)d_in[1];
    const float* sinA  = (const float*)d_in[2];
    const float* bias  = (const float*)d_in[3];
    const float* gamma = (const float*)d_in[4];
    const float* beta  = (const float*)d_in[5];
    float* out = (float*)d_out;

    __bf16* Bp = (__bf16*)d_ws;   // 1 MB: 32 chunks x 128 o x 128 k (bf16)

    fkan_pack_b<<<dim3((NCHUNK * O_DIM * KC) / 8 / 256), dim3(256), 0, stream>>>(cosA, sinA, Bp);
    fkan_main<<<dim3(N_TOK / BN), dim3(512), 0, stream>>>(x, Bp, bias, gamma, beta, out);
}